// Round 3
// baseline (220.236 us; speedup 1.0000x reference)
//
#include <hip/hip_runtime.h>
#include <cstdint>

#define SEQ    8192
#define DIN    1024
#define DOUT   128
#define NSPLIT 8
#define KVTILE 64
#define SM_SCALE 0.08838834764831845f   // 1/sqrt(128)
#define LOG2E    1.4426950408889634f
#define RESCALE_THR 8.0f

typedef unsigned short u16;
typedef __bf16 bf16x8 __attribute__((ext_vector_type(8)));
typedef float  f32x4  __attribute__((ext_vector_type(4)));
typedef unsigned short u16x8 __attribute__((ext_vector_type(8)));
typedef unsigned short u16x4 __attribute__((ext_vector_type(4)));

// f32 -> bf16 via native cast (compiler emits v_cvt_pk_bf16_f32, RNE)
__device__ __forceinline__ u16 bfc(float f) {
  return __builtin_bit_cast(u16, (__bf16)f);
}
__device__ __forceinline__ float bf2f(u16 u) {
  union { uint32_t u; float f; } c; c.u = ((uint32_t)u) << 16; return c.f;
}

__device__ __forceinline__ bf16x8 ldsu8(const u16* base, int byteoff) {
  return __builtin_bit_cast(bf16x8,
    *reinterpret_cast<const u16x8*>(reinterpret_cast<const char*>(base) + byteoff));
}
__device__ __forceinline__ bf16x8 glbu8(const u16* p) {
  return __builtin_bit_cast(bf16x8, *reinterpret_cast<const u16x8*>(p));
}

// ---------------------------------------------------------------- kernel 0
// W [1024][128] fp32  ->  Wt [3][128][1024] bf16 (transposed)
__global__ __launch_bounds__(256) void k_wtrans(const float* __restrict__ wq,
                                                const float* __restrict__ wk,
                                                const float* __restrict__ wv,
                                                u16* __restrict__ Wt) {
  const float* w = (blockIdx.y == 0) ? wq : (blockIdx.y == 1) ? wk : wv;
  int idx = blockIdx.x * 256 + threadIdx.x;      // over DIN*DOUT
  int k = idx >> 7, n = idx & 127;
  Wt[(size_t)blockIdx.y * (DOUT * DIN) + (size_t)n * DIN + k] = bfc(w[idx]);
}

// ---------------------------------------------------------------- kernel 1
// Fused GEMM C[8192][384] = X[8192][1024] * [Wq|Wk|Wv].
// No LDS, no barriers: A-fragments loaded per-lane from global (L1-resident
// across the 4 n-range waves that share rows); Wt streamed from L2.
// Block 512 thr (8 waves) = 2 m-groups x 4 n-ranges; M-tile 32; grid 256.
__global__ __launch_bounds__(512) void k_qkv(const float* __restrict__ x,
                                             const u16* __restrict__ Wt,
                                             u16* __restrict__ Q,
                                             u16* __restrict__ K,
                                             u16* __restrict__ Vt) {
  const int tid  = threadIdx.x;
  const int lane = tid & 63, wave = tid >> 6;
  const int lm   = lane & 15, g = lane >> 4;
  const int mg   = wave >> 2;          // 0..1  (m-group: 16 rows each)
  const int nr   = (wave & 3) * 96;    // n-range base (96 cols per wave)
  const int m0   = blockIdx.x * 32;
  const int mrow = m0 + mg * 16 + lm;
  const float* xp = x + (size_t)mrow * DIN + 8 * g;

  f32x4 acc[6];
#pragma unroll
  for (int nb = 0; nb < 6; ++nb) acc[nb] = (f32x4){0.f, 0.f, 0.f, 0.f};

  for (int kc = 0; kc < DIN / 64; ++kc) {
    bf16x8 a[2];
#pragma unroll
    for (int t = 0; t < 2; ++t) {
      const float* p = xp + kc * 64 + t * 32;
      float4 lo = *reinterpret_cast<const float4*>(p);
      float4 hi = *reinterpret_cast<const float4*>(p + 4);
      u16x8 v = { bfc(lo.x), bfc(lo.y), bfc(lo.z), bfc(lo.w),
                  bfc(hi.x), bfc(hi.y), bfc(hi.z), bfc(hi.w) };
      a[t] = __builtin_bit_cast(bf16x8, v);
    }
#pragma unroll
    for (int nb = 0; nb < 6; ++nb) {
      const u16* wp = Wt + (size_t)(nr + nb * 16 + lm) * DIN + kc * 64 + 8 * g;
#pragma unroll
      for (int t = 0; t < 2; ++t) {
        bf16x8 b = glbu8(wp + t * 32);
        acc[nb] = __builtin_amdgcn_mfma_f32_16x16x32_bf16(a[t], b, acc[nb], 0, 0, 0);
      }
    }
  }

  // epilogue: C/D layout col=lane&15, row=(lane>>4)*4+reg  [HW-verified]
#pragma unroll
  for (int nb = 0; nb < 6; ++nb) {
    int n = nr + nb * 16 + lm;
    int which = n >> 7, col = n & 127;   // uniform per n-block
#pragma unroll
    for (int r = 0; r < 4; ++r) {
      int m = m0 + mg * 16 + g * 4 + r;
      u16 val = bfc(acc[nb][r]);
      if (which == 0)       Q[(size_t)m * DOUT + col] = val;
      else if (which == 1)  K[(size_t)m * DOUT + col] = val;
      else                  Vt[(size_t)col * SEQ + m] = val;
    }
  }
}

// ---------------------------------------------------------------- kernel 2
// Flash attention partials. Block 256 (4 waves), Q-tile 64 (16 rows/wave),
// KV-tile 64 in LDS (XOR-swizzled). grid (SEQ/64, NSPLIT=8) = 1024 blocks
// = 4 blocks/CU (LDS-capped). Defer-max rescale (T13), setprio on MFMA (T5).
__global__ __launch_bounds__(256) void k_attn(const u16* __restrict__ Q,
                                              const u16* __restrict__ K,
                                              const u16* __restrict__ Vt,
                                              u16* __restrict__ Op,
                                              float* __restrict__ Mb,
                                              float* __restrict__ Lb) {
  __shared__ __attribute__((aligned(16))) u16 Ks[64 * 128];    // 16 KB
  __shared__ __attribute__((aligned(16))) u16 Vts[128 * 64];   // 16 KB
  __shared__ __attribute__((aligned(16))) u16 Ps[4][16 * 64];  //  8 KB
  const int tid  = threadIdx.x;
  const int lane = tid & 63, wave = tid >> 6;
  const int lm   = lane & 15, g = lane >> 4;
  const int m0   = blockIdx.x * 64;
  const int split = blockIdx.y;
  const int kvbase = split * (SEQ / NSPLIT);

  // Q fragments, resident in registers for the whole kernel
  bf16x8 qf[4];
  {
    const u16* qp = Q + (size_t)(m0 + wave * 16 + lm) * DOUT + 8 * g;
#pragma unroll
    for (int t = 0; t < 4; ++t) qf[t] = glbu8(qp + t * 32);
  }

  f32x4 o[8];
#pragma unroll
  for (int nb = 0; nb < 8; ++nb) o[nb] = (f32x4){0.f, 0.f, 0.f, 0.f};
  float mr[4] = {-1e30f, -1e30f, -1e30f, -1e30f};
  float lr[4] = {0.f, 0.f, 0.f, 0.f};

  for (int it = 0; it < (SEQ / NSPLIT) / KVTILE; ++it) {
    const int kv0 = kvbase + it * KVTILE;
    __syncthreads();
    // stage K tile [64][128] (row stride 256B, swizzle granule 16B)
#pragma unroll
    for (int p = 0; p < 4; ++p) {
      int row = p * 16 + (tid >> 4), gg = tid & 15;
      u16x8 v = *reinterpret_cast<const u16x8*>(
          K + (size_t)(kv0 + row) * DOUT + gg * 8);
      *reinterpret_cast<u16x8*>(reinterpret_cast<char*>(Ks) + row * 256 +
                                ((gg * 16) ^ ((row & 7) << 4))) = v;
    }
    // stage V^T tile [128][64] (row stride 128B)
#pragma unroll
    for (int p = 0; p < 4; ++p) {
      int n = p * 32 + (tid >> 3), gg = tid & 7;
      u16x8 v = *reinterpret_cast<const u16x8*>(
          Vt + (size_t)n * SEQ + kv0 + gg * 8);
      *reinterpret_cast<u16x8*>(reinterpret_cast<char*>(Vts) + n * 128 +
                                ((gg * 16) ^ ((n & 7) << 4))) = v;
    }
    __syncthreads();

    // ---- S = Q K^T * scale  (4 col-blocks x K=128)
    f32x4 s[4];
    __builtin_amdgcn_s_setprio(1);
#pragma unroll
    for (int cb = 0; cb < 4; ++cb) {
      f32x4 a = (f32x4){0.f, 0.f, 0.f, 0.f};
      int krow = cb * 16 + lm;
#pragma unroll
      for (int t = 0; t < 4; ++t) {
        bf16x8 b = ldsu8(Ks, krow * 256 +
                             (((t * 32 + 8 * g) * 2) ^ ((krow & 7) << 4)));
        a = __builtin_amdgcn_mfma_f32_16x16x32_bf16(qf[t], b, a, 0, 0, 0);
      }
      s[cb] = a * SM_SCALE;
    }
    __builtin_amdgcn_s_setprio(0);

    // ---- online softmax, defer-max (T13). Row owned by lane: q = g*4+r.
    float rmax[4];
#pragma unroll
    for (int r = 0; r < 4; ++r) {
      float rm = fmaxf(fmaxf(s[0][r], s[1][r]), fmaxf(s[2][r], s[3][r]));
#pragma unroll
      for (int off = 1; off < 16; off <<= 1) rm = fmaxf(rm, __shfl_xor(rm, off));
      rmax[r] = rm;
    }
    float exc = fmaxf(fmaxf(rmax[0] - mr[0], rmax[1] - mr[1]),
                      fmaxf(rmax[2] - mr[2], rmax[3] - mr[3]));
    if (__any(exc > RESCALE_THR)) {     // rare after the first tile
#pragma unroll
      for (int r = 0; r < 4; ++r) {
        float mn = fmaxf(mr[r], rmax[r]);
        float alpha = exp2f((mr[r] - mn) * LOG2E);
        mr[r] = mn;
        lr[r] *= alpha;
#pragma unroll
        for (int nb = 0; nb < 8; ++nb) o[nb][r] *= alpha;
      }
    }
    float pv[4][4];
#pragma unroll
    for (int r = 0; r < 4; ++r) {
      float rs = 0.f;
#pragma unroll
      for (int cb = 0; cb < 4; ++cb) {
        float p = exp2f((s[cb][r] - mr[r]) * LOG2E);   // bounded by e^THR
        pv[cb][r] = p;
        rs += p;
      }
#pragma unroll
      for (int off = 1; off < 16; off <<= 1) rs += __shfl_xor(rs, off);
      lr[r] += rs;
    }

    // ---- P -> per-wave LDS (bf16), swizzled like the others
    u16* pw = Ps[wave];
#pragma unroll
    for (int cb = 0; cb < 4; ++cb)
#pragma unroll
      for (int r = 0; r < 4; ++r) {
        int row = g * 4 + r, col = cb * 16 + lm;
        *reinterpret_cast<u16*>(reinterpret_cast<char*>(pw) + row * 128 +
                                ((col * 2) ^ ((row & 7) << 4))) = bfc(pv[cb][r]);
      }
    __syncthreads();   // orders P writes before P reads (uniform)

    // ---- O += P V   (A = P rows, B = V^T rows = d-columns)
    __builtin_amdgcn_s_setprio(1);
#pragma unroll
    for (int t = 0; t < 2; ++t) {
      bf16x8 pa = ldsu8(pw, lm * 128 +
                            (((t * 32 + 8 * g) * 2) ^ ((lm & 7) << 4)));
#pragma unroll
      for (int nb = 0; nb < 8; ++nb) {
        int vrow = nb * 16 + lm;
        bf16x8 vb = ldsu8(Vts, vrow * 128 +
                              (((t * 32 + 8 * g) * 2) ^ ((vrow & 7) << 4)));
        o[nb] = __builtin_amdgcn_mfma_f32_16x16x32_bf16(pa, vb, o[nb], 0, 0, 0);
      }
    }
    __builtin_amdgcn_s_setprio(0);
  }

  // ---- store partials (bf16)
  const size_t ob = (size_t)split * SEQ * DOUT;
#pragma unroll
  for (int nb = 0; nb < 8; ++nb)
#pragma unroll
    for (int r = 0; r < 4; ++r) {
      int m = m0 + wave * 16 + g * 4 + r;
      Op[ob + (size_t)m * DOUT + nb * 16 + lm] = bfc(o[nb][r]);
    }
  if (lm == 0) {
#pragma unroll
    for (int r = 0; r < 4; ++r) {
      int m = m0 + wave * 16 + g * 4 + r;
      Mb[split * SEQ + m] = mr[r];
      Lb[split * SEQ + m] = lr[r];
    }
  }
}

// ---------------------------------------------------------------- kernel 3
__global__ __launch_bounds__(256) void k_combine(const u16* __restrict__ Op,
                                                 const float* __restrict__ Mb,
                                                 const float* __restrict__ Lb,
                                                 float* __restrict__ out) {
  int idx = blockIdx.x * 256 + threadIdx.x;   // over SEQ*DOUT
  int srow = idx >> 7;
  float M = -1e30f;
#pragma unroll
  for (int s = 0; s < NSPLIT; ++s) M = fmaxf(M, Mb[s * SEQ + srow]);
  float num = 0.f, den = 0.f;
  const size_t st = (size_t)SEQ * DOUT;
#pragma unroll
  for (int s = 0; s < NSPLIT; ++s) {
    float e = exp2f((Mb[s * SEQ + srow] - M) * LOG2E);
    den += Lb[s * SEQ + srow] * e;
    num += bf2f(Op[s * st + idx]) * e;
  }
  out[idx] = num / den;
}

// ---------------------------------------------------------------- launch
extern "C" void kernel_launch(void* const* d_in, const int* in_sizes, int n_in,
                              void* d_out, int out_size, void* d_ws, size_t ws_size,
                              hipStream_t stream) {
  const float* x  = (const float*)d_in[0];
  const float* wq = (const float*)d_in[1];
  const float* wk = (const float*)d_in[2];
  const float* wv = (const float*)d_in[3];
  char* ws = (char*)d_ws;

  // workspace layout (bytes), total 23.25 MiB (same as prior passing round):
  //  [0,    768K)          Wt bf16 [3][128][1024]
  //  [768K, +2M)           Q  bf16 [8192][128]
  //  [768K+2M,  +2M)       K  bf16 [8192][128]
  //  [768K+4M,  +2M)       Vt bf16 [128][8192]
  //  [768K+6M,  +16M)      Op bf16 [8][8192][128]
  //  [768K+22M, +256K)     Mb f32 [8][8192]
  //  [768K+22M+256K,+256K) Lb f32 [8][8192]
  const size_t MB = (size_t)1 << 20;
  u16*   Wt = (u16*)(ws);
  u16*   Q  = (u16*)(ws + 768 * 1024);
  u16*   K  = (u16*)(ws + 768 * 1024 + 2 * MB);
  u16*   Vt = (u16*)(ws + 768 * 1024 + 4 * MB);
  u16*   Op = (u16*)(ws + 768 * 1024 + 6 * MB);
  float* Mb = (float*)(ws + 768 * 1024 + 22 * MB);
  float* Lb = (float*)(ws + 768 * 1024 + 22 * MB + 256 * 1024);
  float* out = (float*)d_out;

  k_wtrans<<<dim3((DIN * DOUT) / 256, 3), 256, 0, stream>>>(wq, wk, wv, Wt);
  k_qkv<<<dim3(SEQ / 32), 512, 0, stream>>>(x, Wt, Q, K, Vt);
  k_attn<<<dim3(SEQ / 64, NSPLIT), 256, 0, stream>>>(Q, K, Vt, Op, Mb, Lb);
  k_combine<<<dim3((SEQ * DOUT) / 256), 256, 0, stream>>>(Op, Mb, Lb, out);
}